// Round 5
// baseline (858.553 us; speedup 1.0000x reference)
//
#include <hip/hip_runtime.h>

#define K_CLUSTERS 512
#define FDIM 64
#define ROWS 128  // rows per argmin block; grid = N/ROWS = 1024

typedef float vf4 __attribute__((ext_vector_type(4)));

// Transpose W [F=64][K=512] -> Wt [K][F] (for epilogue gather), wsq[k].
// UNCHANGED (absmax 0.0 proven).
__global__ __launch_bounds__(64) void vq_prep(const float* __restrict__ W,
                                              float* __restrict__ Wt,
                                              float* __restrict__ wsq) {
    int k = blockIdx.x;
    int f = threadIdx.x;
    float w = W[f * K_CLUSTERS + k];
    Wt[k * FDIM + f] = w;
    float s = w * w;
#pragma unroll
    for (int off = 32; off > 0; off >>= 1) s += __shfl_xor(s, off, 64);
    if (f == 0) wsq[k] = s;
}

// sumz[i] = ||z_i||^2 with numpy pairwise order (8 accumulators, tree
// combine), contract off -- identical chain to rounds 1-4 (absmax 0.0).
__global__ __launch_bounds__(256) void vq_sumz(const float* __restrict__ z,
                                               float* __restrict__ sumz) {
    int i = blockIdx.x * 256 + threadIdx.x;
    float zr[FDIM];
    const vf4* z4 = (const vf4*)(z + (size_t)i * FDIM);
#pragma unroll
    for (int f4 = 0; f4 < 16; f4++) {
        vf4 v = z4[f4];
        zr[4 * f4 + 0] = v.x; zr[4 * f4 + 1] = v.y;
        zr[4 * f4 + 2] = v.z; zr[4 * f4 + 3] = v.w;
    }
    float s;
    {
#pragma clang fp contract(off)
        float r0 = zr[0] * zr[0], r1 = zr[1] * zr[1], r2 = zr[2] * zr[2], r3 = zr[3] * zr[3];
        float r4 = zr[4] * zr[4], r5 = zr[5] * zr[5], r6 = zr[6] * zr[6], r7 = zr[7] * zr[7];
#pragma unroll
        for (int b = 8; b < 64; b += 8) {
            r0 += zr[b + 0] * zr[b + 0]; r1 += zr[b + 1] * zr[b + 1];
            r2 += zr[b + 2] * zr[b + 2]; r3 += zr[b + 3] * zr[b + 3];
            r4 += zr[b + 4] * zr[b + 4]; r5 += zr[b + 5] * zr[b + 5];
            r6 += zr[b + 6] * zr[b + 6]; r7 += zr[b + 7] * zr[b + 7];
        }
        s = ((r0 + r1) + (r2 + r3)) + ((r4 + r5) + (r6 + r7));
    }
    sumz[i] = s;
}

// Cluster-parallel argmin: thread (wave q, lane l) owns clusters
// c0=128q+l, c1=c0+64 with their W rows in 128 VGPRs (coalesced load from
// the ORIGINAL W layout: lane stride = 4 B). The z-row address in the hot
// loop is wave-uniform -> scalar loads (SGPR operand into v_fma): no LDS,
// no per-lane VMEM. Every fma instr = 64 useful cluster-dots.
// Per-(row,cluster) arithmetic chain bit-identical to round 1.
// Reduction = lex-min on (d, k): exactly np.argmin's first-index rule.
__global__ __launch_bounds__(256) void vq_argmin_c(const float* __restrict__ z,
                                                   const float* __restrict__ W,
                                                   const float* __restrict__ wsq,
                                                   const float* __restrict__ sumz,
                                                   float* __restrict__ out_idx) {
    __shared__ float sd[4][ROWS];
    __shared__ int sk[4][ROWS];

    const int tid = threadIdx.x;
    const int q = tid >> 6;   // wave -> cluster-quarter
    const int l = tid & 63;
    const int c0 = (q << 7) + l;
    const int c1 = c0 + 64;

    float w0[FDIM], w1[FDIM];
#pragma unroll
    for (int f = 0; f < FDIM; f++) {
        w0[f] = W[f * K_CLUSTERS + c0];  // coalesced: lane stride 4 B
        w1[f] = W[f * K_CLUSTERS + c1];
    }
    const float q0 = wsq[c0], q1 = wsq[c1];

    const int rowBase = blockIdx.x * ROWS;
    for (int r = 0; r < ROWS; r++) {
        const int row = rowBase + r;
        const float* __restrict__ zp = z + (size_t)row * FDIM;  // wave-uniform
        const float s = sumz[row];                               // wave-uniform
        float dot0 = 0.0f, dot1 = 0.0f;
#pragma unroll
        for (int f = 0; f < FDIM; f++) {
            float zv = zp[f];
            dot0 = fmaf(zv, w0[f], dot0);  // ascending-f chain == round 1
            dot1 = fmaf(zv, w1[f], dot1);
        }
        float d0 = fmaf(-2.0f, dot0, s) + q0;
        float d1 = fmaf(-2.0f, dot1, s) + q1;
        float bd = d0;
        int bk = c0;
        if (d1 < bd) { bd = d1; bk = c1; }  // c0 < c1: strict < keeps first index
#pragma unroll
        for (int off = 1; off < 64; off <<= 1) {
            float od = __shfl_xor(bd, off, 64);
            int ok = __shfl_xor(bk, off, 64);
            if (od < bd || (od == bd && ok < bk)) { bd = od; bk = ok; }
        }
        if (l == 0) { sd[q][r] = bd; sk[q][r] = bk; }
    }
    __syncthreads();
    if (tid < ROWS) {
        float bd = sd[0][tid];
        int bk = sk[0][tid];
#pragma unroll
        for (int qq = 1; qq < 4; qq++) {
            float d = sd[qq][tid];
            int kk = sk[qq][tid];
            if (d < bd || (d == bd && kk < bk)) { bd = d; bk = kk; }
        }
        out_idx[rowBase + tid] = (float)bk;
    }
}

// Fully-coalesced epilogue (bit-exact, unchanged from round 3).
__global__ __launch_bounds__(256) void vq_epilogue(const float* __restrict__ z,
                                                   const float* __restrict__ Wt,
                                                   const float* __restrict__ idxf,
                                                   float* __restrict__ out_zq,
                                                   float* __restrict__ out_diff) {
    int t = blockIdx.x * 256 + threadIdx.x;
    int row = t >> 4;
    int c = t & 15;
    int k = (int)idxf[row];
    vf4 zv = ((const vf4*)z)[t];
    vf4 wv = *(const vf4*)(Wt + ((size_t)k << 6) + (c << 2));
    vf4 zq, df;
    {
#pragma clang fp contract(off)
        vf4 d1 = wv - zv;
        zq = zv + d1;
        df = d1 * d1;
    }
    __builtin_nontemporal_store(zq, (vf4*)out_zq + t);
    __builtin_nontemporal_store(df, (vf4*)out_diff + t);
}

// One-hot: 32 B/thread nontemporal, writes every element (no memset pass).
__global__ __launch_bounds__(256) void vq_onehot(const float* __restrict__ idxf,
                                                 float* __restrict__ enc) {
    int tid = blockIdx.x * 256 + threadIdx.x;  // over N*64 8-float chunks
    int row = tid >> 6;
    int c8 = tid & 63;
    int kk = (int)idxf[row];
    int c = kk - c8 * 8;
    vf4 a, b;
    a.x = (c == 0) ? 1.0f : 0.0f;
    a.y = (c == 1) ? 1.0f : 0.0f;
    a.z = (c == 2) ? 1.0f : 0.0f;
    a.w = (c == 3) ? 1.0f : 0.0f;
    b.x = (c == 4) ? 1.0f : 0.0f;
    b.y = (c == 5) ? 1.0f : 0.0f;
    b.z = (c == 6) ? 1.0f : 0.0f;
    b.w = (c == 7) ? 1.0f : 0.0f;
    vf4* p = (vf4*)enc + ((size_t)tid << 1);
    __builtin_nontemporal_store(a, p);
    __builtin_nontemporal_store(b, p + 1);
}

extern "C" void kernel_launch(void* const* d_in, const int* in_sizes, int n_in,
                              void* d_out, int out_size, void* d_ws, size_t ws_size,
                              hipStream_t stream) {
    const float* z = (const float*)d_in[0];
    const float* W = (const float*)d_in[1];
    int N = in_sizes[0] / FDIM;  // 131072

    float* out = (float*)d_out;
    float* out_zq = out;
    float* out_idx = out_zq + (size_t)N * FDIM;
    float* enc = out_idx + N;
    float* out_diff = enc + (size_t)N * K_CLUSTERS;

    float* Wt = (float*)d_ws;
    float* wsq = Wt + K_CLUSTERS * FDIM;
    // sumz scratch lives in the enc output region (N*512 floats available);
    // it is consumed by vq_argmin_c BEFORE vq_onehot overwrites enc.
    float* sumz = enc;

    vq_prep<<<K_CLUSTERS, 64, 0, stream>>>(W, Wt, wsq);
    vq_sumz<<<N / 256, 256, 0, stream>>>(z, sumz);
    vq_argmin_c<<<N / ROWS, 256, 0, stream>>>(z, W, wsq, sumz, out_idx);
    vq_epilogue<<<N * 16 / 256, 256, 0, stream>>>(z, Wt, out_idx, out_zq, out_diff);
    vq_onehot<<<N * 64 / 256, 256, 0, stream>>>(out_idx, enc);
}

// Round 7
// 585.285 us; speedup vs baseline: 1.4669x; 1.4669x over previous
//
#include <hip/hip_runtime.h>

#define K_CLUSTERS 512
#define FDIM 64
#define ROWS 128  // rows per fused block; grid = N/ROWS = 1024

typedef float vf4 __attribute__((ext_vector_type(4)));

// Transpose W [F=64][K=512] -> Wt [K][F] (for epilogue gather), wsq[k].
// UNCHANGED (absmax 0.0 proven).
__global__ __launch_bounds__(64) void vq_prep(const float* __restrict__ W,
                                              float* __restrict__ Wt,
                                              float* __restrict__ wsq) {
    int k = blockIdx.x;
    int f = threadIdx.x;
    float w = W[f * K_CLUSTERS + k];
    Wt[k * FDIM + f] = w;
    float s = w * w;
#pragma unroll
    for (int off = 32; off > 0; off >>= 1) s += __shfl_xor(s, off, 64);
    if (f == 0) wsq[k] = s;
}

// Fused: argmin + zq + diff + one-hot, one block per 128 rows.
// - wave q's lane l owns clusters c0=128q+l, c1=c0+64 (w rows in 128 VGPRs,
//   coalesced loads from original W layout).
// - z rows staged in LDS once; hot loop reads are wave-uniform ds_read_b128
//   broadcasts (~6.6 cyc, calibrated from round 1).
// - __launch_bounds__(256,2): VGPR cap 256 -> no scratch spill (the failure
//   mode of rounds 4 & 5: compiler capped VGPR at 148/72 and spilled arrays).
// All arithmetic chains bit-identical to the proven rounds (absmax 0.0):
// ascending-f fmaf dot; fmaf(-2,dot,s)+wsq; 8-acc pairwise sumz; contract-off
// epilogue; lex-min (d,k) == np.argmin first-index rule (real fp32 ties occur).
__global__ __launch_bounds__(256, 2) void vq_fused(const float* __restrict__ z,
                                                   const float* __restrict__ W,
                                                   const float* __restrict__ Wt,
                                                   const float* __restrict__ wsq,
                                                   float* __restrict__ out_zq,
                                                   float* __restrict__ out_idx,
                                                   float* __restrict__ enc,
                                                   float* __restrict__ out_diff) {
    __shared__ float sZ[ROWS * FDIM];   // 32 KB z tile
    __shared__ float ssum[ROWS];        // sumz per row
    __shared__ float sd[4][ROWS];       // per-wave best distance
    __shared__ int sk[4][ROWS];         // per-wave best index
    __shared__ int skfin[ROWS];         // merged argmin

    const int tid = threadIdx.x;
    const int q = tid >> 6;  // wave index -> cluster group
    const int l = tid & 63;
    const int c0 = (q << 7) + l;
    const int c1 = c0 + 64;
    const int rowBase = blockIdx.x * ROWS;

    // ---- Stage z tile (coalesced float4) ----
    {
        const vf4* zg = (const vf4*)(z + (size_t)rowBase * FDIM);
        vf4* dst = (vf4*)sZ;
#pragma unroll
        for (int j = 0; j < 8; j++) dst[tid + 256 * j] = zg[tid + 256 * j];
    }

    // ---- Load owned cluster rows into VGPRs (one-time, coalesced) ----
    float w0[FDIM], w1[FDIM];
#pragma unroll
    for (int f = 0; f < FDIM; f++) {
        w0[f] = W[f * K_CLUSTERS + c0];
        w1[f] = W[f * K_CLUSTERS + c1];
    }
    const float q0 = wsq[c0], q1 = wsq[c1];

    __syncthreads();

    // ---- sumz for this block's rows: exact numpy pairwise chain ----
    if (tid < ROWS) {
        const float* zr = sZ + tid * FDIM;
        float sres;
        {
#pragma clang fp contract(off)
            float r0 = zr[0] * zr[0], r1 = zr[1] * zr[1], r2 = zr[2] * zr[2], r3 = zr[3] * zr[3];
            float r4 = zr[4] * zr[4], r5 = zr[5] * zr[5], r6 = zr[6] * zr[6], r7 = zr[7] * zr[7];
#pragma unroll
            for (int b = 8; b < 64; b += 8) {
                r0 += zr[b + 0] * zr[b + 0]; r1 += zr[b + 1] * zr[b + 1];
                r2 += zr[b + 2] * zr[b + 2]; r3 += zr[b + 3] * zr[b + 3];
                r4 += zr[b + 4] * zr[b + 4]; r5 += zr[b + 5] * zr[b + 5];
                r6 += zr[b + 6] * zr[b + 6]; r7 += zr[b + 7] * zr[b + 7];
            }
            sres = ((r0 + r1) + (r2 + r3)) + ((r4 + r5) + (r6 + r7));
        }
        ssum[tid] = sres;
    }
    __syncthreads();

    // ---- Hot loop: one row per iteration, broadcast z, 128 dots/thread ----
    const vf4* sZ4 = (const vf4*)sZ;
    for (int r = 0; r < ROWS; r++) {
        const float s = ssum[r];
        float dot0 = 0.0f, dot1 = 0.0f;
#pragma unroll
        for (int f4 = 0; f4 < 16; f4++) {
            vf4 zb = sZ4[r * 16 + f4];  // wave-uniform broadcast
            dot0 = fmaf(zb.x, w0[4 * f4 + 0], dot0);
            dot0 = fmaf(zb.y, w0[4 * f4 + 1], dot0);
            dot0 = fmaf(zb.z, w0[4 * f4 + 2], dot0);
            dot0 = fmaf(zb.w, w0[4 * f4 + 3], dot0);
            dot1 = fmaf(zb.x, w1[4 * f4 + 0], dot1);
            dot1 = fmaf(zb.y, w1[4 * f4 + 1], dot1);
            dot1 = fmaf(zb.z, w1[4 * f4 + 2], dot1);
            dot1 = fmaf(zb.w, w1[4 * f4 + 3], dot1);
        }
        float d0 = fmaf(-2.0f, dot0, s) + q0;
        float d1 = fmaf(-2.0f, dot1, s) + q1;
        float bd = d0;
        int bk = c0;
        if (d1 < bd) { bd = d1; bk = c1; }  // c0 < c1: strict < = first index
#pragma unroll
        for (int off = 1; off < 64; off <<= 1) {
            float od = __shfl_xor(bd, off, 64);
            int ok = __shfl_xor(bk, off, 64);
            if (od < bd || (od == bd && ok < bk)) { bd = od; bk = ok; }
        }
        if (l == 0) { sd[q][r] = bd; sk[q][r] = bk; }
    }
    __syncthreads();

    // ---- Merge the 4 wave-partials (lex-min => np first-index rule) ----
    if (tid < ROWS) {
        float bd = sd[0][tid];
        int bk = sk[0][tid];
#pragma unroll
        for (int qq = 1; qq < 4; qq++) {
            float d = sd[qq][tid];
            int kk = sk[qq][tid];
            if (d < bd || (d == bd && kk < bk)) { bd = d; bk = kk; }
        }
        skfin[tid] = bk;
        out_idx[rowBase + tid] = (float)bk;
    }
    __syncthreads();

    // ---- Epilogue: zq & diff (z from LDS, w gather from Wt; bit-exact) ----
#pragma unroll
    for (int j = 0; j < 8; j++) {
        int t = tid + 256 * j;        // over ROWS*16 float4 chunks
        int row = t >> 4;
        int c = t & 15;
        int k = skfin[row];
        vf4 zv = sZ4[t];
        vf4 wv = *(const vf4*)(Wt + ((size_t)k << 6) + (c << 2));
        vf4 zq, df;
        {
#pragma clang fp contract(off)
            vf4 d1 = wv - zv;
            zq = zv + d1;
            df = d1 * d1;
        }
        ((vf4*)out_zq)[(size_t)rowBase * 16 + t] = zq;
        ((vf4*)out_diff)[(size_t)rowBase * 16 + t] = df;
    }

    // ---- One-hot: coalesced plain stores (A/B vs prior NT path) ----
    vf4* enc4 = (vf4*)enc + (size_t)rowBase * 128;
#pragma unroll 4
    for (int t = tid; t < ROWS * 128; t += 256) {
        int row = t >> 7;
        int c4 = t & 127;
        int c = skfin[row] - (c4 << 2);
        vf4 v;
        v.x = (c == 0) ? 1.0f : 0.0f;
        v.y = (c == 1) ? 1.0f : 0.0f;
        v.z = (c == 2) ? 1.0f : 0.0f;
        v.w = (c == 3) ? 1.0f : 0.0f;
        enc4[t] = v;
    }
}

extern "C" void kernel_launch(void* const* d_in, const int* in_sizes, int n_in,
                              void* d_out, int out_size, void* d_ws, size_t ws_size,
                              hipStream_t stream) {
    const float* z = (const float*)d_in[0];
    const float* W = (const float*)d_in[1];
    int N = in_sizes[0] / FDIM;  // 131072

    float* out = (float*)d_out;
    float* out_zq = out;
    float* out_idx = out_zq + (size_t)N * FDIM;
    float* enc = out_idx + N;
    float* out_diff = enc + (size_t)N * K_CLUSTERS;

    float* Wt = (float*)d_ws;
    float* wsq = Wt + K_CLUSTERS * FDIM;

    vq_prep<<<K_CLUSTERS, 64, 0, stream>>>(W, Wt, wsq);
    vq_fused<<<N / ROWS, 256, 0, stream>>>(z, W, Wt, wsq, out_zq, out_idx, enc, out_diff);
}